// Round 1
// baseline (320.265 us; speedup 1.0000x reference)
//
#include <hip/hip_runtime.h>
#include <hip/hip_bf16.h>

// Problem constants (from reference): B=512, T=64, A=32, H=512, E=32
#define B_ 512
#define T_ 64
#define A_ 32
#define H_ 512
#define E_ 32
#define MAX_TASKS 272   // sum_e ceil(cnt_e/2) <= 256 + 16

typedef unsigned short u16;
typedef unsigned int u32;
typedef __attribute__((ext_vector_type(8))) short short8;   // 8 bf16 = 4 VGPRs (MFMA A/B frag)
typedef __attribute__((ext_vector_type(4))) float floatx4;  // MFMA C/D frag

static __device__ __forceinline__ u16 f2bf(float f) {
    u32 u = __builtin_bit_cast(u32, f);
    u += 0x7fffu + ((u >> 16) & 1u);   // RNE
    return (u16)(u >> 16);
}

// ---------------------------------------------------------------------------
// Kernel 1: group samples by expert (counting sort) + build M-block task list.
// One block, 512 threads. tasks[i] = {expert, slot0, nsamp (0/1/2), pad}.
// ---------------------------------------------------------------------------
__global__ void group_kernel(const int* __restrict__ cat_ids,
                             int* __restrict__ sample_list,
                             int4* __restrict__ tasks) {
    __shared__ int cnt[E_], off[E_], cur[E_];
    int tid = threadIdx.x;
    if (tid < E_) { cnt[tid] = 0; cur[tid] = 0; }
    __syncthreads();
    int e = cat_ids[tid];               // tid in [0,512) == B_
    atomicAdd(&cnt[e], 1);
    __syncthreads();
    if (tid == 0) {
        int run = 0;
        for (int i = 0; i < E_; i++) { off[i] = run; run += cnt[i]; }
        int ti = 0;
        for (int i = 0; i < E_; i++) {
            int c = cnt[i];
            for (int j = 0; j < c; j += 2)
                tasks[ti++] = make_int4(i, off[i] + j, (c - j >= 2) ? 2 : 1, 0);
        }
        for (; ti < MAX_TASKS; ti++) tasks[ti] = make_int4(0, 0, 0, 0);
    }
    __syncthreads();
    int p = atomicAdd(&cur[e], 1);
    sample_list[off[e] + p] = tid;
}

// ---------------------------------------------------------------------------
// Kernel 2: per-sample tau embedding (512-vec, shared across T) + GEMM1
// a_emb = actions @ W1[e] + b1[e]  (fp32 VALU, K=32), stored bf16.
// Grid: 512 blocks x 256 threads. Thread tid owns output cols {tid, tid+256};
// W1 columns live in 64 VGPRs; actions row broadcast from LDS.
// ---------------------------------------------------------------------------
__global__ __launch_bounds__(256) void embed_kernel(
        const float* __restrict__ actions, const float* __restrict__ timesteps,
        const int* __restrict__ cat_ids, const float* __restrict__ W1,
        const float* __restrict__ b1, u16* __restrict__ a_emb,
        u16* __restrict__ tau_emb) {
    int b = blockIdx.x;
    int tid = threadIdx.x;
    int e = cat_ids[b];
    float tval = timesteps[b];

    // tau: freqs = exp(-ln(10000)*i/256), i in [0,256); [sin | cos]
    {
        float freq = expf(-9.210340371976184f * (float)tid * (1.0f / 256.0f));
        float ang = tval * freq;
        tau_emb[b * H_ + tid]       = f2bf(sinf(ang));
        tau_emb[b * H_ + 256 + tid] = f2bf(cosf(ang));
    }

    __shared__ float act[T_ * A_];
    const float* asrc = actions + (size_t)b * T_ * A_;
    for (int i = tid; i < T_ * A_; i += 256) act[i] = asrc[i];
    __syncthreads();

    const float* w1 = W1 + (size_t)e * A_ * H_;
    int n0 = tid, n1 = tid + 256;
    float wA[A_], wB[A_];
#pragma unroll
    for (int k = 0; k < A_; k++) {
        wA[k] = w1[k * H_ + n0];
        wB[k] = w1[k * H_ + n1];
    }
    float bA = b1[e * H_ + n0], bB = b1[e * H_ + n1];
    u16* orow = a_emb + (size_t)b * T_ * H_;
    for (int tt = 0; tt < T_; tt++) {
        float accA = bA, accB = bB;
#pragma unroll
        for (int k = 0; k < A_; k++) {
            float a = act[tt * A_ + k];   // LDS broadcast (same addr all lanes)
            accA = fmaf(a, wA[k], accA);
            accB = fmaf(a, wB[k], accB);
        }
        orow[tt * H_ + n0] = f2bf(accA);
        orow[tt * H_ + n1] = f2bf(accB);
    }
}

// ---------------------------------------------------------------------------
// Kernels 3/4: expert-grouped MFMA GEMM. Block tile: M=128 (2 samples), N=128.
// K-step 32 (one 16x16x32 mfma depth). x-tile and transposed W-tile staged in
// LDS with stride 40 bf16 (80B: 16B-aligned b128, 2-way bank conflicts only).
// Wave w owns rows [32w,32w+32) x all 128 cols -> 16 C-tiles, 64 acc VGPRs.
// For GEMM2 (DIN=1024) the K in [512,1024) rows come from the per-sample tau
// vector (broadcast over T), so x in ws holds only a_emb.
// ---------------------------------------------------------------------------
template <int DIN, bool HAS_TAU, bool DO_SWISH, bool OUT_BF16>
__global__ __launch_bounds__(256, 2) void moe_gemm(
        const u16* __restrict__ xsrc, const u16* __restrict__ tau,
        const float* __restrict__ W, const float* __restrict__ bias,
        const int* __restrict__ sample_list, const int4* __restrict__ tasks,
        void* __restrict__ outp) {
    int4 task = tasks[blockIdx.y];
    int ns = task.z;
    if (ns == 0) return;
    int e = task.x;
    int s0 = sample_list[task.y];
    int s1 = (ns > 1) ? sample_list[task.y + 1] : s0;  // duplicate: reads valid, stores masked
    int n0 = blockIdx.x * 128;

    int tid = threadIdx.x;
    int lane = tid & 63, wv = tid >> 6, quad = lane >> 4, c15 = lane & 15;

    __shared__ __align__(16) u16 xs[128 * 40];  // [row][k] k=0..31, stride 40
    __shared__ __align__(16) u16 wt[128 * 40];  // [n][k]   transposed W tile

    floatx4 acc[2][8];
    floatx4 zero4 = {0.f, 0.f, 0.f, 0.f};
#pragma unroll
    for (int i = 0; i < 2; i++)
#pragma unroll
        for (int j = 0; j < 8; j++) acc[i][j] = zero4;

    const float* wbase = W + (size_t)e * DIN * H_ + n0;
    int x_row = tid >> 2, x_oct = tid & 3;          // staging unit tid (+256)
    int w_nn = tid & 127, w_kh = tid >> 7;          // wt staging: col nn, k-half

    for (int k0 = 0; k0 < DIN; k0 += 32) {
        // ---- stage x tile (128 rows x 32 k, bf16) : 2 x b128 per thread ----
        bool use_tau = HAS_TAU && (k0 >= 512);
#pragma unroll
        for (int h = 0; h < 2; h++) {
            int row = x_row + h * 64;
            int s = (row < 64) ? s0 : s1;
            int t = row & 63;
            int kg = k0 + x_oct * 8;
            const u16* src = use_tau ? (tau + (size_t)s * H_ + (kg - 512))
                                     : (xsrc + ((size_t)s * T_ + t) * H_ + kg);
            short8 v = *(const short8*)src;
            *(short8*)&xs[row * 40 + x_oct * 8] = v;
        }
        // ---- stage W tile transposed: thread reads 16 k-rows at fixed n ----
        {
            const float* wp = wbase + (size_t)(k0 + w_kh * 16) * H_ + w_nn;
            short8 h0, h1;
#pragma unroll
            for (int j = 0; j < 8; j++) {
                h0[j] = (short)f2bf(wp[(size_t)j * H_]);
                h1[j] = (short)f2bf(wp[(size_t)(j + 8) * H_]);
            }
            *(short8*)&wt[w_nn * 40 + w_kh * 16]     = h0;
            *(short8*)&wt[w_nn * 40 + w_kh * 16 + 8] = h1;
        }
        __syncthreads();

        // ---- fragments: A[m=c15][k=quad*8+j], B[k=quad*8+j][n=c15] ----
        short8 af[2], bf[8];
#pragma unroll
        for (int mt = 0; mt < 2; mt++) {
            int row = wv * 32 + mt * 16 + c15;
            af[mt] = *(const short8*)&xs[row * 40 + quad * 8];
        }
#pragma unroll
        for (int nt = 0; nt < 8; nt++) {
            int nr = nt * 16 + c15;
            bf[nt] = *(const short8*)&wt[nr * 40 + quad * 8];
        }
#pragma unroll
        for (int mt = 0; mt < 2; mt++)
#pragma unroll
            for (int nt = 0; nt < 8; nt++)
                acc[mt][nt] = __builtin_amdgcn_mfma_f32_16x16x32_bf16(
                        af[mt], bf[nt], acc[mt][nt], 0, 0, 0);
        __syncthreads();
    }

    // ---- epilogue: C/D layout col=c15, row=quad*4+r ----
    const float* bp = bias + (size_t)e * H_;
#pragma unroll
    for (int mt = 0; mt < 2; mt++) {
        int rbase = wv * 32 + mt * 16 + quad * 4;
        int side = rbase >> 6;            // 0: sample s0 rows, 1: s1 rows
        if (side == 1 && ns == 1) continue;
        int s = side ? s1 : s0;
#pragma unroll
        for (int nt = 0; nt < 8; nt++) {
            int col = n0 + nt * 16 + c15;
            float bv = bp[col];
#pragma unroll
            for (int r = 0; r < 4; r++) {
                int t = (rbase + r) & 63;
                float v = acc[mt][nt][r] + bv;
                if (DO_SWISH) v = v / (1.0f + expf(-v));   // x*sigmoid(x)
                size_t oidx = ((size_t)s * T_ + t) * H_ + col;
                if (OUT_BF16) ((u16*)outp)[oidx] = f2bf(v);
                else          ((float*)outp)[oidx] = v;
            }
        }
    }
}

// ---------------------------------------------------------------------------
extern "C" void kernel_launch(void* const* d_in, const int* in_sizes, int n_in,
                              void* d_out, int out_size, void* d_ws, size_t ws_size,
                              hipStream_t stream) {
    const float* actions   = (const float*)d_in[0];
    const float* timesteps = (const float*)d_in[1];
    const int*   cat_ids   = (const int*)d_in[2];
    const float* W1 = (const float*)d_in[3];
    const float* b1 = (const float*)d_in[4];
    const float* W2 = (const float*)d_in[5];
    const float* b2 = (const float*)d_in[6];
    const float* W3 = (const float*)d_in[7];
    const float* b3 = (const float*)d_in[8];

    // ws layout: a_emb 32MB | y 32MB | tau 512KB | sample_list | tasks
    char* ws = (char*)d_ws;
    u16* a_emb = (u16*)ws;                                        // 512*64*512 bf16
    u16* y     = (u16*)(ws + (size_t)32 * 1024 * 1024);           // 512*64*512 bf16
    u16* tau   = (u16*)(ws + (size_t)64 * 1024 * 1024);           // 512*512 bf16
    int* sample_list = (int*)(ws + (size_t)64 * 1024 * 1024 + 512 * 1024);
    int4* tasks = (int4*)(ws + (size_t)64 * 1024 * 1024 + 512 * 1024 + 4096);

    hipLaunchKernelGGL(group_kernel, dim3(1), dim3(512), 0, stream,
                       cat_ids, sample_list, tasks);
    hipLaunchKernelGGL(embed_kernel, dim3(512), dim3(256), 0, stream,
                       actions, timesteps, cat_ids, W1, b1, a_emb, tau);
    hipLaunchKernelGGL((moe_gemm<2 * H_, true, true, true>), dim3(4, MAX_TASKS),
                       dim3(256), 0, stream,
                       a_emb, tau, W2, b2, sample_list, tasks, (void*)y);
    hipLaunchKernelGGL((moe_gemm<H_, false, false, false>), dim3(4, MAX_TASKS),
                       dim3(256), 0, stream,
                       y, (const u16*)nullptr, W3, b3, sample_list, tasks, d_out);
}